// Round 3
// baseline (277.899 us; speedup 1.0000x reference)
//
#include <hip/hip_runtime.h>

#define N_NODES 100000
#define NEDGE   1600000
#define D       32
#define SCAN_B  256
#define NBLK_SCAN ((N_NODES + SCAN_B - 1) / SCAN_B)   // 391

// ---------- CSR build ----------

__global__ void hist_kernel(const int* __restrict__ dst, int* __restrict__ deg) {
    int e = blockIdx.x * blockDim.x + threadIdx.x;
    if (e < NEDGE) atomicAdd(&deg[dst[e]], 1);
}

__global__ void scan1_kernel(const int* __restrict__ deg, int* __restrict__ off,
                             int* __restrict__ part) {
    __shared__ int s[SCAN_B];
    int i = blockIdx.x * SCAN_B + threadIdx.x;
    int v = (i < N_NODES) ? deg[i] : 0;
    s[threadIdx.x] = v;
    __syncthreads();
    for (int o = 1; o < SCAN_B; o <<= 1) {
        int t = (threadIdx.x >= o) ? s[threadIdx.x - o] : 0;
        __syncthreads();
        s[threadIdx.x] += t;
        __syncthreads();
    }
    if (i < N_NODES) off[i] = s[threadIdx.x] - v;          // exclusive within block
    if (threadIdx.x == SCAN_B - 1) part[blockIdx.x] = s[SCAN_B - 1];
}

__global__ void scan2_kernel(int* part) {                  // single block of 512
    __shared__ int s[512];
    int v = (threadIdx.x < NBLK_SCAN) ? part[threadIdx.x] : 0;
    s[threadIdx.x] = v;
    __syncthreads();
    for (int o = 1; o < 512; o <<= 1) {
        int t = (threadIdx.x >= o) ? s[threadIdx.x - o] : 0;
        __syncthreads();
        s[threadIdx.x] += t;
        __syncthreads();
    }
    if (threadIdx.x < NBLK_SCAN) part[threadIdx.x] = s[threadIdx.x] - v;  // exclusive
}

__global__ void scan3_kernel(int* __restrict__ off, const int* __restrict__ part) {
    int i = blockIdx.x * SCAN_B + threadIdx.x;
    if (i < N_NODES) off[i] += part[blockIdx.x];
}

// cur[] is pre-seeded with off[] (d2d copy); slot = post-increment cursor.
// One packed 8B store per edge instead of two 4B stores 6.4MB apart.
__global__ void fill_kernel(const int* __restrict__ src, const int* __restrict__ dst,
                            const float* __restrict__ w,
                            int* __restrict__ cur, int2* __restrict__ csr_sw) {
    int e = blockIdx.x * blockDim.x + threadIdx.x;
    if (e >= NEDGE) return;
    int d = dst[e];
    int slot = atomicAdd(&cur[d], 1);
    csr_sw[slot] = make_int2(src[e], __float_as_int(w[e]));
}

// ---------- gather SpMM (no atomics) ----------
// 8 threads per node; each owns a float4 slice of the 32-wide feature row.
__global__ void spmm_gather_kernel(const int* __restrict__ off, const int* __restrict__ deg,
                                   const int2* __restrict__ csr_sw,
                                   const float* __restrict__ x, float* __restrict__ out) {
    int gid = blockIdx.x * blockDim.x + threadIdx.x;
    if (gid >= N_NODES * 8) return;
    int node = gid >> 3;
    int c    = gid & 7;
    int start = off[node];
    int len   = deg[node];
    float4 acc = {0.f, 0.f, 0.f, 0.f};
    for (int k = 0; k < len; ++k) {
        int2  sw = csr_sw[start + k];
        float wt = __int_as_float(sw.y);
        const float4 xv = *reinterpret_cast<const float4*>(&x[(long)sw.x * D + c * 4]);
        acc.x += wt * xv.x;
        acc.y += wt * xv.y;
        acc.z += wt * xv.z;
        acc.w += wt * xv.w;
    }
    *reinterpret_cast<float4*>(&out[(long)node * D + c * 4]) = acc;
}

// ---------- fallback (atomic scatter) if ws too small ----------
__global__ void spmm_scatter_kernel(const int* __restrict__ src, const int* __restrict__ dst,
                                    const float* __restrict__ w, const float* __restrict__ x,
                                    float* __restrict__ out) {
    long gid = (long)blockIdx.x * blockDim.x + threadIdx.x;
    if (gid >= (long)NEDGE * 8) return;
    int e = (int)(gid >> 3);
    int c = (int)(gid & 7);
    int s = src[e], d = dst[e];
    float wt = w[e];
    const float4 xv = *reinterpret_cast<const float4*>(&x[(long)s * D + c * 4]);
    float* o = &out[(long)d * D + c * 4];
    atomicAdd(o + 0, wt * xv.x);
    atomicAdd(o + 1, wt * xv.y);
    atomicAdd(o + 2, wt * xv.z);
    atomicAdd(o + 3, wt * xv.w);
}

extern "C" void kernel_launch(void* const* d_in, const int* in_sizes, int n_in,
                              void* d_out, int out_size, void* d_ws, size_t ws_size,
                              hipStream_t stream) {
    const float* x    = (const float*)d_in[0];
    const int*   esrc = (const int*)d_in[1];
    const int*   edst = (const int*)d_in[2];
    const float* ew   = (const float*)d_in[3];
    float* out = (float*)d_out;

    char* ws = (char*)d_ws;
    const size_t y_bytes    = (size_t)N_NODES * D * sizeof(float);   // 12.8 MB
    const size_t n_ints     = (size_t)N_NODES * sizeof(int);         // 400 KB
    const size_t part_bytes = 512 * sizeof(int);
    const size_t e_sw       = (size_t)NEDGE * sizeof(int2);          // 12.8 MB

    size_t o = 0;
    float* y      = (float*)(ws + o); o += y_bytes;
    int*   deg    = (int*)  (ws + o); o += n_ints;
    int*   off    = (int*)  (ws + o); o += n_ints;
    int*   cur    = (int*)  (ws + o); o += n_ints;
    int*   part   = (int*)  (ws + o); o += part_bytes;
    int2*  csr_sw = (int2*) (ws + o); o += e_sw;

    if (ws_size < o) {
        hipMemsetAsync(y, 0, y_bytes, stream);
        hipMemsetAsync(out, 0, y_bytes, stream);
        const long total = (long)NEDGE * 8;
        const int blocks = (int)((total + 255) / 256);
        spmm_scatter_kernel<<<blocks, 256, 0, stream>>>(esrc, edst, ew, x, y);
        spmm_scatter_kernel<<<blocks, 256, 0, stream>>>(esrc, edst, ew, y, out);
        return;
    }

    hipMemsetAsync(deg, 0, n_ints, stream);

    const int eblocks = (NEDGE + 255) / 256;
    hist_kernel<<<eblocks, 256, 0, stream>>>(edst, deg);
    scan1_kernel<<<NBLK_SCAN, SCAN_B, 0, stream>>>(deg, off, part);
    scan2_kernel<<<1, 512, 0, stream>>>(part);
    scan3_kernel<<<NBLK_SCAN, SCAN_B, 0, stream>>>(off, part);
    hipMemcpyAsync(cur, off, n_ints, hipMemcpyDeviceToDevice, stream);
    fill_kernel<<<eblocks, 256, 0, stream>>>(esrc, edst, ew, cur, csr_sw);

    const int gthreads = N_NODES * 8;
    const int gblocks  = (gthreads + 255) / 256;
    spmm_gather_kernel<<<gblocks, 256, 0, stream>>>(off, deg, csr_sw, x, y);
    spmm_gather_kernel<<<gblocks, 256, 0, stream>>>(off, deg, csr_sw, y, out);
}

// Round 4
// 151.542 us; speedup vs baseline: 1.8338x; 1.8338x over previous
//
#include <hip/hip_runtime.h>

#define N_NODES 100000
#define NEDGE   1600000
#define D       32

#define BSHIFT   7
#define BNODES   128                       // nodes per bucket
#define NBUCKET  ((N_NODES + BNODES - 1) / BNODES)   // 782
#define NB_PAD   784
#define EPB      4096                      // edges per block in bin pass
#define CBLK     ((NEDGE + EPB - 1) / EPB) // 391
#define CAP      3072                      // max edges per bucket for LDS path (mean 2048, sd 45)

// ---------- Kernel A: per-bucket edge histogram ----------
__global__ void bucket_hist_kernel(const int* __restrict__ dst, int* __restrict__ bucket_cnt) {
    __shared__ int h[NB_PAD];
    for (int i = threadIdx.x; i < NB_PAD; i += blockDim.x) h[i] = 0;
    __syncthreads();
    for (int e = blockIdx.x * blockDim.x + threadIdx.x; e < NEDGE; e += gridDim.x * blockDim.x)
        atomicAdd(&h[dst[e] >> BSHIFT], 1);
    __syncthreads();
    for (int i = threadIdx.x; i < NB_PAD; i += blockDim.x)
        if (h[i]) atomicAdd(&bucket_cnt[i], h[i]);
}

// ---------- Kernel B: exclusive scan of 784 bucket counts (1 block, 1024 thr) ----------
__global__ void bucket_scan_kernel(const int* __restrict__ bucket_cnt,
                                   int* __restrict__ bucket_off, int* __restrict__ bucket_cur) {
    __shared__ int s[1024];
    int tid = threadIdx.x;
    int v = (tid < NB_PAD) ? bucket_cnt[tid] : 0;
    s[tid] = v;
    __syncthreads();
    for (int o = 1; o < 1024; o <<= 1) {
        int t = (tid >= o) ? s[tid - o] : 0;
        __syncthreads();
        s[tid] += t;
        __syncthreads();
    }
    if (tid < NB_PAD) {
        int excl = s[tid] - v;
        bucket_off[tid] = excl;
        bucket_cur[tid] = excl;
    }
}

// ---------- Kernel C: bin edges into bucket-contiguous runs ----------
// packed: x = src | (dst_local << 17)   (src < 2^17, dst_local < 128), y = w bits
__global__ void bin_edges_kernel(const int* __restrict__ src, const int* __restrict__ dst,
                                 const float* __restrict__ w,
                                 int* __restrict__ bucket_cur, int2* __restrict__ binned) {
    __shared__ int cnt[NB_PAD];
    __shared__ int base[NB_PAD];
    int tid = threadIdx.x;
    for (int i = tid; i < NB_PAD; i += blockDim.x) cnt[i] = 0;
    __syncthreads();
    int e0 = blockIdx.x * EPB;
    for (int i = tid; i < EPB; i += blockDim.x) {
        int e = e0 + i;
        if (e < NEDGE) atomicAdd(&cnt[dst[e] >> BSHIFT], 1);
    }
    __syncthreads();
    for (int i = tid; i < NB_PAD; i += blockDim.x) {
        int c = cnt[i];
        base[i] = c ? atomicAdd(&bucket_cur[i], c) : 0;
        cnt[i] = 0;   // reuse as local cursor
    }
    __syncthreads();
    for (int i = tid; i < EPB; i += blockDim.x) {
        int e = e0 + i;
        if (e < NEDGE) {
            int d = dst[e];
            int b = d >> BSHIFT;
            int r = atomicAdd(&cnt[b], 1);
            binned[base[b] + r] = make_int2(src[e] | ((d & (BNODES - 1)) << 17),
                                            __float_as_int(w[e]));
        }
    }
}

// ---------- Kernel D: per-bucket CSR slice build (coalesced out) ----------
__global__ void build_csr_kernel(const int* __restrict__ bucket_off, const int* __restrict__ bucket_cnt,
                                 const int2* __restrict__ binned,
                                 int2* __restrict__ csr, int* __restrict__ off, int* __restrict__ deg) {
    __shared__ int2 stage[CAP];
    __shared__ int2 sorted[CAP];
    __shared__ int ndcnt[BNODES];
    __shared__ int ndoff[BNODES];
    __shared__ int s[BNODES];

    int b = blockIdx.x;
    int tid = threadIdx.x;
    int start = bucket_off[b];
    int cnt_b = bucket_cnt[b];
    bool fast = (cnt_b <= CAP);

    if (tid < BNODES) ndcnt[tid] = 0;
    if (fast)
        for (int i = tid; i < cnt_b; i += blockDim.x) stage[i] = binned[start + i];
    __syncthreads();

    // node histogram
    if (fast) {
        for (int i = tid; i < cnt_b; i += blockDim.x)
            atomicAdd(&ndcnt[(stage[i].x >> 17) & (BNODES - 1)], 1);
    } else {
        for (int i = tid; i < cnt_b; i += blockDim.x)
            atomicAdd(&ndcnt[(binned[start + i].x >> 17) & (BNODES - 1)], 1);
    }
    __syncthreads();

    // exclusive scan of 128 node counts
    int v = (tid < BNODES) ? ndcnt[tid] : 0;
    if (tid < BNODES) s[tid] = v;
    __syncthreads();
    for (int o = 1; o < BNODES; o <<= 1) {
        int t = (tid < BNODES && tid >= o) ? s[tid - o] : 0;
        __syncthreads();
        if (tid < BNODES) s[tid] += t;
        __syncthreads();
    }
    if (tid < BNODES) {
        ndoff[tid] = s[tid] - v;
        int node = b * BNODES + tid;
        if (node < N_NODES) {
            off[node] = start + ndoff[tid];
            deg[node] = v;
        }
        ndcnt[tid] = 0;   // reuse as cursor
    }
    __syncthreads();

    // scatter to node-sorted order, then coalesced write-out
    if (fast) {
        for (int i = tid; i < cnt_b; i += blockDim.x) {
            int2 p = stage[i];
            int dl = (p.x >> 17) & (BNODES - 1);
            int r = atomicAdd(&ndcnt[dl], 1);
            sorted[ndoff[dl] + r] = make_int2(p.x & 0x1FFFF, p.y);
        }
        __syncthreads();
        for (int i = tid; i < cnt_b; i += blockDim.x) csr[start + i] = sorted[i];
    } else {
        // freak-bucket fallback: scattered global stores (correct, slow)
        for (int i = tid; i < cnt_b; i += blockDim.x) {
            int2 p = binned[start + i];
            int dl = (p.x >> 17) & (BNODES - 1);
            int r = atomicAdd(&ndcnt[dl], 1);
            csr[start + ndoff[dl] + r] = make_int2(p.x & 0x1FFFF, p.y);
        }
    }
}

// ---------- gather SpMM (no atomics) ----------
__global__ void spmm_gather_kernel(const int* __restrict__ off, const int* __restrict__ deg,
                                   const int2* __restrict__ csr_sw,
                                   const float* __restrict__ x, float* __restrict__ out) {
    int gid = blockIdx.x * blockDim.x + threadIdx.x;
    if (gid >= N_NODES * 8) return;
    int node = gid >> 3;
    int c    = gid & 7;
    int start = off[node];
    int len   = deg[node];
    float4 acc = {0.f, 0.f, 0.f, 0.f};
    for (int k = 0; k < len; ++k) {
        int2  sw = csr_sw[start + k];
        float wt = __int_as_float(sw.y);
        const float4 xv = *reinterpret_cast<const float4*>(&x[(long)sw.x * D + c * 4]);
        acc.x += wt * xv.x;
        acc.y += wt * xv.y;
        acc.z += wt * xv.z;
        acc.w += wt * xv.w;
    }
    *reinterpret_cast<float4*>(&out[(long)node * D + c * 4]) = acc;
}

// ---------- fallback (atomic scatter) if ws too small ----------
__global__ void spmm_scatter_kernel(const int* __restrict__ src, const int* __restrict__ dst,
                                    const float* __restrict__ w, const float* __restrict__ x,
                                    float* __restrict__ out) {
    long gid = (long)blockIdx.x * blockDim.x + threadIdx.x;
    if (gid >= (long)NEDGE * 8) return;
    int e = (int)(gid >> 3);
    int c = (int)(gid & 7);
    int s = src[e], d = dst[e];
    float wt = w[e];
    const float4 xv = *reinterpret_cast<const float4*>(&x[(long)s * D + c * 4]);
    float* o = &out[(long)d * D + c * 4];
    atomicAdd(o + 0, wt * xv.x);
    atomicAdd(o + 1, wt * xv.y);
    atomicAdd(o + 2, wt * xv.z);
    atomicAdd(o + 3, wt * xv.w);
}

extern "C" void kernel_launch(void* const* d_in, const int* in_sizes, int n_in,
                              void* d_out, int out_size, void* d_ws, size_t ws_size,
                              hipStream_t stream) {
    const float* x    = (const float*)d_in[0];
    const int*   esrc = (const int*)d_in[1];
    const int*   edst = (const int*)d_in[2];
    const float* ew   = (const float*)d_in[3];
    float* out = (float*)d_out;

    char* ws = (char*)d_ws;
    const size_t y_bytes = (size_t)N_NODES * D * sizeof(float);   // 12.8 MB (== binned bytes)
    const size_t n_ints  = (size_t)N_NODES * sizeof(int);         // 400 KB
    const size_t b_ints  = (size_t)NB_PAD * sizeof(int);
    const size_t e_sw    = (size_t)NEDGE * sizeof(int2);          // 12.8 MB

    size_t o = 0;
    float* y          = (float*)(ws + o); o += y_bytes;           // aliases `binned`
    int2*  csr        = (int2*) (ws + o); o += e_sw;
    int*   off        = (int*)  (ws + o); o += n_ints;
    int*   deg        = (int*)  (ws + o); o += n_ints;
    int*   bucket_cnt = (int*)  (ws + o); o += b_ints;
    int*   bucket_off = (int*)  (ws + o); o += b_ints;
    int*   bucket_cur = (int*)  (ws + o); o += b_ints;
    int2*  binned     = (int2*)y;   // reuse: binned dead once csr built, y live after

    if (ws_size < o) {
        hipMemsetAsync(y, 0, y_bytes, stream);
        hipMemsetAsync(out, 0, y_bytes, stream);
        const long total = (long)NEDGE * 8;
        const int blocks = (int)((total + 255) / 256);
        spmm_scatter_kernel<<<blocks, 256, 0, stream>>>(esrc, edst, ew, x, y);
        spmm_scatter_kernel<<<blocks, 256, 0, stream>>>(esrc, edst, ew, y, out);
        return;
    }

    hipMemsetAsync(bucket_cnt, 0, b_ints, stream);

    bucket_hist_kernel<<<256, 256, 0, stream>>>(edst, bucket_cnt);
    bucket_scan_kernel<<<1, 1024, 0, stream>>>(bucket_cnt, bucket_off, bucket_cur);
    bin_edges_kernel<<<CBLK, 256, 0, stream>>>(esrc, edst, ew, bucket_cur, binned);
    build_csr_kernel<<<NBUCKET, 256, 0, stream>>>(bucket_off, bucket_cnt, binned, csr, off, deg);

    const int gblocks = (N_NODES * 8 + 255) / 256;
    spmm_gather_kernel<<<gblocks, 256, 0, stream>>>(off, deg, csr, x, y);
    spmm_gather_kernel<<<gblocks, 256, 0, stream>>>(off, deg, csr, y, out);
}